// Round 1
// baseline (240.813 us; speedup 1.0000x reference)
//
#include <hip/hip_runtime.h>

namespace {

constexpr int B  = 8;
constexpr int L  = 4096;
constexpr int D  = 1024;
constexpr int P  = L / 2;        // 2048 pair-rows in pair space
constexpr int TJ = 32;           // columns per tile
constexpr int TP = 128;          // output pair-rows per tile (divides P)
constexpr int RTOT = TP + TJ;    // staged source pair-rows (>= TP+TJ-1)
constexpr int NT = 256;

// out[b, 2p+t, j] = {min,max}(v[b, 2q, j], v[b, 2q+1, j]) with q = (p - h_j) mod P,
// h_j = max(j-1, 0). Shear of slope 1 pair/column -> stage source rectangle in LDS.
__global__ __launch_bounds__(NT)
void swd_kernel(const float* __restrict__ v, float* __restrict__ out) {
  const int j0 = blockIdx.x * TJ;
  const int p0 = blockIdx.y * TP;
  const int b  = blockIdx.z;

  __shared__ float lds_m[RTOT][TJ];
  __shared__ float lds_M[RTOT][TJ];

  // h over this tile spans [hmin, hmax]; hmax = j0+TJ-2 holds for j0==0 too.
  const int hmax = j0 + TJ - 2;
  const int r0   = p0 - hmax;    // first staged source pair-row (mod P)

  const float* __restrict__ vb = v + (size_t)b * L * D + j0;

  // Stage: load source pairs (rows 2q, 2q+1), fold min/max, store to LDS.
  // Wave: lanes 0..31 -> one k-row (128B contiguous), lanes 32..63 -> next. 2-way bank alias = free.
  for (int idx = threadIdx.x; idx < RTOT * TJ; idx += NT) {
    const int k  = idx / TJ;
    const int jj = idx - k * TJ;
    const int q  = (r0 + k) & (P - 1);       // power-of-2 mod, correct for negatives
    const size_t base = (size_t)(2 * q) * D + jj;
    const float a0 = vb[base];
    const float a1 = vb[base + D];
    lds_m[k][jj] = fminf(a0, a1);
    lds_M[k][jj] = fmaxf(a0, a1);
  }
  __syncthreads();

  // Drain: coalesced writes of both rows of each output pair.
  float* __restrict__ ob = out + (size_t)b * L * D + j0;
  for (int idx = threadIdx.x; idx < TP * TJ; idx += NT) {
    const int pp = idx / TJ;
    const int jj = idx - pp * TJ;
    const int j  = j0 + jj;
    const int h  = (j == 0) ? 0 : (j - 1);
    const int k  = pp + (hmax - h);          // = (p - h) - r0, in [0, RTOT)
    const size_t o = (size_t)(2 * (p0 + pp)) * D + jj;
    ob[o]     = lds_m[k][jj];
    ob[o + D] = lds_M[k][jj];
  }
}

} // namespace

extern "C" void kernel_launch(void* const* d_in, const int* /*in_sizes*/, int /*n_in*/,
                              void* d_out, int /*out_size*/, void* /*d_ws*/, size_t /*ws_size*/,
                              hipStream_t stream) {
  const float* v = (const float*)d_in[0];
  float* out = (float*)d_out;
  dim3 grid(D / TJ, P / TP, B);   // (32, 16, 8) = 4096 blocks
  swd_kernel<<<grid, NT, 0, stream>>>(v, out);
}

// Round 2
// 233.889 us; speedup vs baseline: 1.0296x; 1.0296x over previous
//
#include <hip/hip_runtime.h>

namespace {

constexpr int B  = 8;
constexpr int L  = 4096;
constexpr int D  = 1024;
constexpr int D4 = D / 4;        // 256 float4 per row
constexpr int P  = L / 2;        // 2048 pair-rows
constexpr int TJ = 32;           // columns per tile
constexpr int G  = TJ / 4;       // 8 float4 groups per tile
constexpr int TP = 128;          // output pairs per tile
constexpr int RTOT = TP + TJ;    // 160 staged source pair-rows
constexpr int LDW  = TJ + 4;     // 36: padded LDS row stride (dwords), 16B-aligned
constexpr int NT = 512;

// out[b, 2p+t, j] = {min,max}(v[b,2q,j], v[b,2q+1,j]), q = (p - h_j) mod P,
// h_j = j-1 (h_0 = 0). Stage axis-aligned min/max rectangle in LDS, resolve
// the 1-pair-per-column shear at drain via per-component row selection.
__global__ __launch_bounds__(NT)
void swd_kernel(const float4* __restrict__ v, float4* __restrict__ out) {
  const int j0 = blockIdx.x * TJ;
  const int p0 = blockIdx.y * TP;
  const int b  = blockIdx.z;

  __shared__ __align__(16) float lds_m[RTOT][LDW];
  __shared__ __align__(16) float lds_M[RTOT][LDW];

  const int hmax = j0 + TJ - 2;
  const int r0   = p0 - hmax;

  const float4* __restrict__ vb = v + (size_t)b * L * D4 + (j0 >> 2);

  // ---- Stage: RTOT rows x G float4 groups; fold pair min/max on the fly.
  for (int idx = threadIdx.x; idx < RTOT * G; idx += NT) {
    const int k  = idx >> 3;          // staged row
    const int fg = idx & 7;           // float4 column group
    const int q  = (r0 + k) & (P - 1);
    const float4 a0 = vb[(size_t)(2 * q) * D4 + fg];
    const float4 a1 = vb[(size_t)(2 * q + 1) * D4 + fg];
    float4 m, M;
    m.x = fminf(a0.x, a1.x); M.x = fmaxf(a0.x, a1.x);
    m.y = fminf(a0.y, a1.y); M.y = fmaxf(a0.y, a1.y);
    m.z = fminf(a0.z, a1.z); M.z = fmaxf(a0.z, a1.z);
    m.w = fminf(a0.w, a1.w); M.w = fmaxf(a0.w, a1.w);
    *(float4*)&lds_m[k][4 * fg] = m;
    *(float4*)&lds_M[k][4 * fg] = M;
  }
  __syncthreads();

  // ---- Drain: each lane owns column quad g and pairs pp0, pp0+1.
  const int g   = threadIdx.x & 7;
  const int c   = threadIdx.x >> 3;     // 0..63
  const int pp0 = c * 2;
  // k_x(pp) = pp + (TJ-1) - 4g : LDS row for component x (general h = j-1)
  const int kx = pp0 + (TJ - 1) - 4 * g;   // in [3, 157]; window kx-3 .. kx+1

  const float4 m0 = *(const float4*)&lds_m[kx - 3][4 * g];
  const float4 m1 = *(const float4*)&lds_m[kx - 2][4 * g];
  const float4 m2 = *(const float4*)&lds_m[kx - 1][4 * g];
  const float4 m3 = *(const float4*)&lds_m[kx    ][4 * g];
  const float4 m4 = *(const float4*)&lds_m[kx + 1][4 * g];
  const float4 M0 = *(const float4*)&lds_M[kx - 3][4 * g];
  const float4 M1 = *(const float4*)&lds_M[kx - 2][4 * g];
  const float4 M2 = *(const float4*)&lds_M[kx - 1][4 * g];
  const float4 M3 = *(const float4*)&lds_M[kx    ][4 * g];
  const float4 M4 = *(const float4*)&lds_M[kx + 1][4 * g];

  const bool sp = (j0 == 0) && (g == 0);   // column 0: h_0 = 0, not -1

  float4 e0, o0, e1, o1;
  e0.x = sp ? m2.x : m3.x; e0.y = m2.y; e0.z = m1.z; e0.w = m0.w;
  o0.x = sp ? M2.x : M3.x; o0.y = M2.y; o0.z = M1.z; o0.w = M0.w;
  e1.x = sp ? m3.x : m4.x; e1.y = m3.y; e1.z = m2.z; e1.w = m1.w;
  o1.x = sp ? M3.x : M4.x; o1.y = M3.y; o1.z = M2.z; o1.w = M1.w;

  float4* __restrict__ ob = out + (size_t)b * L * D4 + (j0 >> 2) + g;
  const size_t ro = (size_t)(2 * (p0 + pp0)) * D4;
  ob[ro]            = e0;
  ob[ro + D4]       = o0;
  ob[ro + 2 * D4]   = e1;
  ob[ro + 3 * D4]   = o1;
}

} // namespace

extern "C" void kernel_launch(void* const* d_in, const int* /*in_sizes*/, int /*n_in*/,
                              void* d_out, int /*out_size*/, void* /*d_ws*/, size_t /*ws_size*/,
                              hipStream_t stream) {
  const float4* v = (const float4*)d_in[0];
  float4* out = (float4*)d_out;
  dim3 grid(D / TJ, P / TP, B);   // (32, 16, 8) = 4096 blocks
  swd_kernel<<<grid, NT, 0, stream>>>(v, out);
}